// Round 7
// baseline (507.575 us; speedup 1.0000x reference)
//
#include <hip/hip_runtime.h>

#define DD 512
#define NNODE 100
#define NH 8

typedef __attribute__((ext_vector_type(4))) float f32x4;
typedef __attribute__((ext_vector_type(8))) short s16x8;

__device__ __forceinline__ unsigned short f2bf(float x) {
  union { float f; unsigned int u; } v; v.f = x;
  unsigned int r = v.u + 0x7fffu + ((v.u >> 16) & 1u);
  return (unsigned short)(r >> 16);
}
__device__ __forceinline__ float bf2f(unsigned short u) {
  union { unsigned int u; float f; } v; v.u = ((unsigned int)u) << 16;
  return v.f;
}

// ---- shared GEMM core: 64x64 tile, 4 waves, bf16 MFMA, 2-phase pipelined ----
struct StageRegs { float4 a4[2]; float as[8]; float4 b4[2]; float bs[8]; };

__device__ __forceinline__ void stage_issue(
    StageRegs& r, const float* __restrict__ A, const float* __restrict__ B,
    const int* __restrict__ gidx, int gmul, int k0, int lda, int ldb,
    int transA, int transB, int m0, int n0)
{
  const int t = threadIdx.x;
  const int tr = t >> 3, kq = t & 7;
  const int bn = t & 63, bk = t >> 6;
  if (!transA) {
#pragma unroll
    for (int rp = 0; rp < 2; ++rp) {
      const int gi = m0 + tr + rp * 32;
      long ab = (long)gi * lda;
      if (gidx) ab += (long)gidx[gi] * gmul;
      r.a4[rp] = *(const float4*)(A + ab + k0 + kq * 4);
    }
  } else {
#pragma unroll
    for (int pp = 0; pp < 8; ++pp)
      r.as[pp] = A[(long)(k0 + bk + pp * 4) * lda + m0 + bn];
  }
  if (transB) {
#pragma unroll
    for (int rp = 0; rp < 2; ++rp)
      r.b4[rp] = *(const float4*)(B + (long)(n0 + tr + rp * 32) * ldb + k0 + kq * 4);
  } else {
#pragma unroll
    for (int pp = 0; pp < 8; ++pp)
      r.bs[pp] = B[(long)(k0 + bk + pp * 4) * ldb + n0 + bn];
  }
}

__device__ __forceinline__ void stage_commit(
    const StageRegs& r, int transA, int transB,
    unsigned short (*As)[40], unsigned short (*Bs)[40])
{
  const int t = threadIdx.x;
  const int tr = t >> 3, kq = t & 7;
  const int bn = t & 63, bk = t >> 6;
  if (!transA) {
#pragma unroll
    for (int rp = 0; rp < 2; ++rp) {
      const float4 av = r.a4[rp];
      unsigned int p0 = (unsigned)f2bf(av.x) | ((unsigned)f2bf(av.y) << 16);
      unsigned int p1 = (unsigned)f2bf(av.z) | ((unsigned)f2bf(av.w) << 16);
      *(uint2*)(&As[tr + rp * 32][kq * 4]) = make_uint2(p0, p1);
    }
  } else {
#pragma unroll
    for (int pp = 0; pp < 8; ++pp) As[bn][bk + pp * 4] = f2bf(r.as[pp]);
  }
  if (transB) {
#pragma unroll
    for (int rp = 0; rp < 2; ++rp) {
      const float4 bv = r.b4[rp];
      unsigned int p0 = (unsigned)f2bf(bv.x) | ((unsigned)f2bf(bv.y) << 16);
      unsigned int p1 = (unsigned)f2bf(bv.z) | ((unsigned)f2bf(bv.w) << 16);
      *(uint2*)(&Bs[tr + rp * 32][kq * 4]) = make_uint2(p0, p1);
    }
  } else {
#pragma unroll
    for (int pp = 0; pp < 8; ++pp) Bs[bn][bk + pp * 4] = f2bf(r.bs[pp]);
  }
}

__device__ __forceinline__ void gemm_core(
    f32x4 acc[2][2], const float* __restrict__ A, const float* __restrict__ B,
    const int* __restrict__ gidx, int gmul, int K, int lda, int ldb,
    int transA, int transB, int m0, int n0,
    unsigned short (*As)[40], unsigned short (*Bs)[40])
{
  const int t = threadIdx.x;
  const int wid = t >> 6, lane = t & 63;
  const int wr = wid >> 1, wc = wid & 1;
  const int r16 = lane & 15, kg = (lane >> 4) * 8;
  StageRegs r;
  stage_issue(r, A, B, gidx, gmul, 0, lda, ldb, transA, transB, m0, n0);
  for (int k0 = 0; k0 < K; k0 += 32) {
    __syncthreads();                       // LDS free (prev tile consumed)
    stage_commit(r, transA, transB, As, Bs);
    __syncthreads();                       // LDS ready
    if (k0 + 32 < K)                       // issue AFTER barrier: stays in flight
      stage_issue(r, A, B, gidx, gmul, k0 + 32, lda, ldb, transA, transB, m0, n0);
    s16x8 a0 = *(const s16x8*)(&As[wr * 32 + r16][kg]);
    s16x8 a1 = *(const s16x8*)(&As[wr * 32 + 16 + r16][kg]);
    s16x8 b0 = *(const s16x8*)(&Bs[wc * 32 + r16][kg]);
    s16x8 b1 = *(const s16x8*)(&Bs[wc * 32 + 16 + r16][kg]);
    acc[0][0] = __builtin_amdgcn_mfma_f32_16x16x32_bf16(a0, b0, acc[0][0], 0, 0, 0);
    acc[0][1] = __builtin_amdgcn_mfma_f32_16x16x32_bf16(a0, b1, acc[0][1], 0, 0, 0);
    acc[1][0] = __builtin_amdgcn_mfma_f32_16x16x32_bf16(a1, b0, acc[1][0], 0, 0, 0);
    acc[1][1] = __builtin_amdgcn_mfma_f32_16x16x32_bf16(a1, b1, acc[1][1], 0, 0, 0);
  }
}

__device__ __forceinline__ void gemm_epilogue(
    f32x4 acc[2][2], void* Cv, int ldc, float alpha, float beta, int obf16,
    int m0, int n0)
{
  const int t = threadIdx.x;
  const int wid = t >> 6, lane = t & 63;
  const int wr = wid >> 1, wc = wid & 1;
  const int r16 = lane & 15;
#pragma unroll
  for (int si = 0; si < 2; ++si)
#pragma unroll
    for (int sj = 0; sj < 2; ++sj)
#pragma unroll
      for (int r = 0; r < 4; ++r) {
        const int row = m0 + wr * 32 + si * 16 + (lane >> 4) * 4 + r;
        const int col = n0 + wc * 32 + sj * 16 + r16;
        const long ci = (long)row * ldc + col;
        float v = alpha * acc[si][sj][r];
        if (obf16) {
          ((unsigned short*)Cv)[ci] = f2bf(v);
        } else {
          float* C = (float*)Cv;
          if (beta != 0.f) v = fmaf(beta, C[ci], v);
          C[ci] = v;
        }
      }
}

__global__ __launch_bounds__(256) void gemm_mfma(
    const float* __restrict__ A, const float* __restrict__ B, void* Cv,
    int K, int lda, int ldb, int ldc,
    long aoffz, long boffz, long coffz,
    int transA, int transB, float alpha, float beta, int obf16)
{
  __shared__ unsigned short As[64][40];
  __shared__ unsigned short Bs[64][40];
  A += (long)blockIdx.z * aoffz;
  B += (long)blockIdx.z * boffz;
  f32x4 acc[2][2] = {};
  gemm_core(acc, A, B, nullptr, 0, K, lda, ldb, transA, transB,
            blockIdx.y * 64, blockIdx.x * 64, As, Bs);
  void* Cz = obf16 ? (void*)((unsigned short*)Cv + (long)blockIdx.z * coffz)
                   : (void*)((float*)Cv + (long)blockIdx.z * coffz);
  gemm_epilogue(acc, Cz, ldc, alpha, beta, obf16, blockIdx.y * 64, blockIdx.x * 64);
}

struct Fold5Args {
  const float* A[5]; const float* B[5]; float* C[5]; float al[5]; int ta[5];
};

// 5 independent 512^3 weight folds (z selects); z may use transA
__global__ __launch_bounds__(256) void fold5_kernel(Fold5Args fa) {
  __shared__ unsigned short As[64][40];
  __shared__ unsigned short Bs[64][40];
  const int z = blockIdx.z;
  f32x4 acc[2][2] = {};
  gemm_core(acc, fa.A[z], fa.B[z], nullptr, 0, 512, 512, 512, fa.ta[z], 0,
            blockIdx.y * 64, blockIdx.x * 64, As, Bs);
  gemm_epilogue(acc, fa.C[z], 512, fa.al[z], 0.f, 0, blockIdx.y * 64, blockIdx.x * 64);
}

// by<32: qbuf = tgt@A1^T + graph@A2^T.  by>=32: M1 = Wo_mha^T @ T1.
__global__ __launch_bounds__(256) void qbufM1_kernel(
    const float* __restrict__ node, const float* __restrict__ graph,
    const int* __restrict__ tidx, const float* __restrict__ A1,
    const float* __restrict__ A2, float* __restrict__ qbuf,
    const float* __restrict__ Wo, const float* __restrict__ T1,
    float* __restrict__ M1)
{
  __shared__ unsigned short As[64][40];
  __shared__ unsigned short Bs[64][40];
  f32x4 acc[2][2] = {};
  const int n0 = blockIdx.x * 64;
  if (blockIdx.y < 32) {
    const int m0 = blockIdx.y * 64;
    gemm_core(acc, node, A1, tidx, DD, DD, NNODE * DD, DD, 0, 1, m0, n0, As, Bs);
    gemm_core(acc, graph, A2, nullptr, 0, DD, DD, DD, 0, 1, m0, n0, As, Bs);
    gemm_epilogue(acc, qbuf, DD, 1.f, 0.f, 0, m0, n0);
  } else {
    const int m0 = (blockIdx.y - 32) * 64;
    gemm_core(acc, Wo, T1, nullptr, 0, 512, 512, 512, 1, 0, m0, n0, As, Bs);
    gemm_epilogue(acc, M1, 512, 1.f, 0.f, 0, m0, n0);
  }
}

// ---- fused attention: single 16KB nf buffer + live prefetch + swizzle.
// One block per batch, 256 thr = 4 waves; launch_bounds forces 4 blocks/CU.
// No mid-chunk waitcnt drains (same-wave LDS RAW is compiler-handled);
// defer-max rescale (T13, THR=8).
__global__ __launch_bounds__(256, 4) void attn_fused(
    const float* __restrict__ node, const unsigned short* __restrict__ qk16,
    unsigned short* __restrict__ nb16, float* __restrict__ ctx)
{
  const int b = blockIdx.x;
  const int t = threadIdx.x;
  const int lane = t & 63;
  const int wid = t >> 6;
  const int r16 = lane & 15;
  const int rg = lane >> 4;

  __shared__ unsigned short nf[16 * 512];   // 16 KB, slot-swizzled
  __shared__ unsigned short qf[16 * 288];   // 9 KB
  __shared__ float Pl[4][16][8];
  __shared__ float rfl[4][8];

  {
    const unsigned short* qb = qk16 + (long)b * (NH * DD);
    for (int slot = t; slot < 512; slot += 256) {
      const int s = slot >> 5;
      const int idx = slot & 31;           // h*4+g
      const int h = idx >> 2, g = idx & 3;
      *(s16x8*)(&qf[s * 288 + idx * 8 + (idx >> 3) * 8]) =
          *(const s16x8*)(qb + h * DD + s * 32 + g * 8);
    }
  }

  const int r0 = t >> 7;
  const int c4 = (t * 4) & 511;
  const int slotbase = ((c4 >> 3) * 16) + r0;
  const int j_c = c4 & 7;
  const int d0 = t * 2;
  const int cslot0 = (d0 >> 3) * 16;
  const int cxor = (d0 >> 3) & 7;
  const int cj = d0 & 7;
  const int qidx = (r16 & 7) * 4 + rg;
  const int qfb = qidx * 8 + (qidx >> 3) * 8;

  const float* nbase = node + (long)b * (NNODE * DD);
  float4 rs[8];
  {
    const int lim = NNODE * DD;
#pragma unroll
    for (int i = 0; i < 8; ++i) {
      const int e = 4 * t + 1024 * i;
      rs[i] = (e < lim) ? *(const float4*)(nbase + e) : make_float4(0.f, 0.f, 0.f, 0.f);
    }
  }

  float m = -3.0e38f, l = 0.f;
  float2 c2[NH];
#pragma unroll
  for (int h = 0; h < NH; ++h) { c2[h].x = 0.f; c2[h].y = 0.f; }
  ushort4 h4s[8];

  for (int c = 0; c < 7; ++c) {
    const int c0 = c * 16;
    // cvt staged regs -> LDS (swizzled); keep bf16 in regs for global store
#pragma unroll
    for (int i = 0; i < 8; ++i) {
      ushort4 h4;
      h4.x = f2bf(rs[i].x); h4.y = f2bf(rs[i].y);
      h4.z = f2bf(rs[i].z); h4.w = f2bf(rs[i].w);
      h4s[i] = h4;
      const int slot = slotbase + 2 * i;
      const int phys = slot ^ ((slot >> 4) & 7);
      *(ushort4*)(&nf[phys * 8 + j_c]) = h4;
    }
    __syncthreads();                        // nf ready (qf too on c==0)
    // issue next-chunk loads AFTER the barrier: stay in flight across compute
    if (c < 6) {
      const int nc0 = c0 + 16;
      const int lim = (NNODE - nc0) * DD;
#pragma unroll
      for (int i = 0; i < 8; ++i) {
        const int e = 4 * t + 1024 * i;
        rs[i] = (e < lim) ? *(const float4*)(nbase + (long)nc0 * DD + e)
                          : make_float4(0.f, 0.f, 0.f, 0.f);
      }
    }
#pragma unroll
    for (int i = 0; i < 8; ++i) {
      const int row = r0 + 2 * i;
      if (c0 + row < NNODE)
        *(ushort4*)(nb16 + ((long)b * NNODE + c0 + row) * DD + c4) = h4s[i];
    }

    // scores via MFMA (per-wave redundant; lanes r16>=8 compute dup heads,
    // masked at Pl write — no divergent zero-predication needed)
    f32x4 acc = {0.f, 0.f, 0.f, 0.f};
#pragma unroll
    for (int s = 0; s < 16; ++s) {
      const int slr = (s * 4 + rg) * 16 + r16;
      const s16x8 av = *(const s16x8*)(&nf[(slr ^ ((s * 4 + rg) & 7)) * 8]);
      const s16x8 bv = *(const s16x8*)(&qf[s * 288 + qfb]);
      acc = __builtin_amdgcn_mfma_f32_16x16x32_bf16(av, bv, acc, 0, 0, 0);
    }
#pragma unroll
    for (int r = 0; r < 4; ++r)
      if (c0 + rg * 4 + r >= NNODE) acc[r] = -3.0e38f;

    // online softmax per head col r16; defer-max: skip rescale while
    // chunk max stays within THR=8 of running max (wave-uniform)
    float cm = fmaxf(fmaxf(acc[0], acc[1]), fmaxf(acc[2], acc[3]));
    cm = fmaxf(cm, __shfl_xor(cm, 16));
    cm = fmaxf(cm, __shfl_xor(cm, 32));
    const bool noresc = (__all(cm <= m + 8.f) != 0);
    if (!noresc) {
      const float mn = fmaxf(m, cm);
      const float rf = __expf(m - mn);
      l *= rf;
      m = mn;
      if (r16 < NH && rg == 0) rfl[wid][r16] = rf;
    }
    float p[4], ps = 0.f;
#pragma unroll
    for (int r = 0; r < 4; ++r) { p[r] = __expf(acc[r] - m); ps += p[r]; }
    ps += __shfl_xor(ps, 16);
    ps += __shfl_xor(ps, 32);
    l += ps;
    if (r16 < NH) {
#pragma unroll
      for (int r = 0; r < 4; ++r) Pl[wid][rg * 4 + r][r16] = p[r];
    }

    // ctx update (swizzled nv reads; Pl reads are broadcast — conflict-free)
    if (!noresc) {
      const f32x4 rf0 = *(const f32x4*)(&rfl[wid][0]);
      const f32x4 rf1 = *(const f32x4*)(&rfl[wid][4]);
#pragma unroll
      for (int h = 0; h < 4; ++h) { c2[h].x *= rf0[h]; c2[h].y *= rf0[h]; }
#pragma unroll
      for (int h = 0; h < 4; ++h) { c2[4 + h].x *= rf1[h]; c2[4 + h].y *= rf1[h]; }
    }
#pragma unroll
    for (int n = 0; n < 16; ++n) {
      const int cphys = (cslot0 + n) ^ cxor;
      const unsigned int nv = *(const unsigned int*)(&nf[cphys * 8 + cj]);
      const float x0 = bf2f((unsigned short)(nv & 0xffffu));
      const float x1 = bf2f((unsigned short)(nv >> 16));
      const f32x4 p0 = *(const f32x4*)(&Pl[wid][n][0]);
      const f32x4 p1 = *(const f32x4*)(&Pl[wid][n][4]);
#pragma unroll
      for (int h = 0; h < 4; ++h) {
        c2[h].x = fmaf(p0[h], x0, c2[h].x);
        c2[h].y = fmaf(p0[h], x1, c2[h].y);
        c2[4 + h].x = fmaf(p1[h], x0, c2[4 + h].x);
        c2[4 + h].y = fmaf(p1[h], x1, c2[4 + h].y);
      }
    }
    __syncthreads();                        // nf consumed -> next cvt may write
  }

  if (r16 < NH && rg == 0) rfl[wid][r16] = 1.f / l;
  __builtin_amdgcn_wave_barrier();          // no-op scheduling hint; LDS RAW auto-waited
  {
    const f32x4 i0 = *(const f32x4*)(&rfl[wid][0]);
    const f32x4 i1 = *(const f32x4*)(&rfl[wid][4]);
    float* cb = ctx + (long)b * (NH * DD) + d0;
#pragma unroll
    for (int h = 0; h < 4; ++h) {
      cb[h * DD] = c2[h].x * i0[h];
      cb[h * DD + 1] = c2[h].y * i0[h];
      cb[(4 + h) * DD] = c2[4 + h].x * i1[h];
      cb[(4 + h) * DD + 1] = c2[4 + h].y * i1[h];
    }
  }
}

// ---- fused logits: MFMA dots from bf16 node + tanh/mask/log_softmax.
// 512 threads: one n-tile per wave (7 of 8 waves), then finalize on wave 0.
__global__ __launch_bounds__(512) void logits_kernel(
    const unsigned short* __restrict__ nb16, const unsigned short* __restrict__ qk216,
    const int* __restrict__ mask, float* __restrict__ out)
{
  const int b = blockIdx.x;
  const int t = threadIdx.x;
  const int wid = t >> 6, lane = t & 63;
  const int r16 = lane & 15, rg = lane >> 4;
  __shared__ float sl[112];
  const unsigned short* qb = qk216 + (long)b * DD + rg * 8;

  if (wid < 7) {
    const int ti = wid;
    const int arow = min(ti * 16 + r16, NNODE - 1);
    const unsigned short* ap = nb16 + ((long)b * NNODE + arow) * DD + rg * 8;
    f32x4 acc = {0.f, 0.f, 0.f, 0.f};
#pragma unroll
    for (int s = 0; s < 16; ++s) {
      const s16x8 av = *(const s16x8*)(ap + s * 32);
      const s16x8 bv = *(const s16x8*)(qb + s * 32);
      acc = __builtin_amdgcn_mfma_f32_16x16x32_bf16(av, bv, acc, 0, 0, 0);
    }
    if (r16 == 0) {
#pragma unroll
      for (int r = 0; r < 4; ++r) {
        const int n = ti * 16 + rg * 4 + r;
        if (n < 112) sl[n] = acc[r];
      }
    }
  }
  __syncthreads();
  if (t < 64) {
    float v0 = -3.0e38f, v1 = -3.0e38f;
    if (lane < NNODE)
      v0 = 10.f * tanhf(sl[lane]) - (float)mask[b * NNODE + lane] * 1e9f;
    if (lane + 64 < NNODE)
      v1 = 10.f * tanhf(sl[lane + 64]) - (float)mask[b * NNODE + lane + 64] * 1e9f;
    float mx = fmaxf(v0, v1);
#pragma unroll
    for (int off = 1; off < 64; off <<= 1) mx = fmaxf(mx, __shfl_xor(mx, off));
    float e = 0.f;
    if (lane < NNODE) e += __expf(v0 - mx);
    if (lane + 64 < NNODE) e += __expf(v1 - mx);
#pragma unroll
    for (int off = 1; off < 64; off <<= 1) e += __shfl_xor(e, off);
    const float lse = mx + __logf(e);
    float* ob = out + (long)b * NNODE;
    if (lane < NNODE) ob[lane] = v0 - lse;
    if (lane + 64 < NNODE) ob[lane + 64] = v1 - lse;
  }
}

extern "C" void kernel_launch(void* const* d_in, const int* in_sizes, int n_in,
                              void* d_out, int out_size, void* d_ws, size_t ws_size,
                              hipStream_t stream) {
  const float* node     = (const float*)d_in[0];
  const float* graph    = (const float*)d_in[1];
  const int*   tidx     = (const int*)d_in[2];
  const int*   mask     = (const int*)d_in[3];
  const float* W_target = (const float*)d_in[4];
  const float* W_global = (const float*)d_in[5];
  const float* W_K1     = (const float*)d_in[6];
  const float* W_K2     = (const float*)d_in[7];
  const float* W_Q      = (const float*)d_in[8];
  const float* W_V      = (const float*)d_in[9];
  const float* Wq_mha   = (const float*)d_in[10];
  const float* Wk_mha   = (const float*)d_in[11];
  const float* Wv_mha   = (const float*)d_in[12];
  const float* Wo_mha   = (const float*)d_in[13];
  float* out = (float*)d_out;

  float* base = (float*)d_ws;
  unsigned short* nb16 = (unsigned short*)base;          // 2048*100*512 bf16
  long off = 2048L * NNODE * DD / 2;                     // in floats
  float* A1 = base + off;        off += 262144;
  float* A2 = base + off;        off += 262144;
  float* Wkc = base + off;       off += 262144;
  float* Wvc = base + off;       off += 262144;
  float* T1 = base + off;        off += 262144;
  float* M1 = base + off;        off += 262144;
  float* qbuf = base + off;      off += 2048L * 512;
  unsigned short* qk16 = (unsigned short*)(base + off);  off += 2048L * 4096 / 2;
  float* ctxb = base + off;      off += 2048L * 4096;
  float* preo = base + off;      off += 2048L * 512;
  unsigned short* qk216 = (unsigned short*)(base + off); off += 2048L * 512 / 2;

  dim3 blk(256);
  const float SH = 0.125f;               // 1/sqrt(64)
  const float SD = 0.044194173824f;      // 1/sqrt(512)

  // level-0 folds: A1=Wq@Wt, A2=Wq@Wg, Wkc=SH*(Wk@WK1), Wvc=Wv@WV, T1=W_Q^T@W_K2
  Fold5Args fa;
  fa.A[0] = Wq_mha;  fa.B[0] = W_target; fa.C[0] = A1;  fa.al[0] = 1.f; fa.ta[0] = 0;
  fa.A[1] = Wq_mha;  fa.B[1] = W_global; fa.C[1] = A2;  fa.al[1] = 1.f; fa.ta[1] = 0;
  fa.A[2] = Wk_mha;  fa.B[2] = W_K1;     fa.C[2] = Wkc; fa.al[2] = SH;  fa.ta[2] = 0;
  fa.A[3] = Wv_mha;  fa.B[3] = W_V;      fa.C[3] = Wvc; fa.al[3] = 1.f; fa.ta[3] = 0;
  fa.A[4] = W_Q;     fa.B[4] = W_K2;     fa.C[4] = T1;  fa.al[4] = 1.f; fa.ta[4] = 1;
  fold5_kernel<<<dim3(8, 8, 5), blk, 0, stream>>>(fa);
  // level-1: qbuf (by<32) and M1 = Wo_mha^T @ T1 (by>=32) in one launch
  qbufM1_kernel<<<dim3(8, 40), blk, 0, stream>>>(node, graph, tidx, A1, A2, qbuf,
                                                 Wo_mha, T1, M1);
  // qk16[b,h,:] = bf16( q[b, head h] @ Wkc[head h rows] )
  gemm_mfma<<<dim3(8, 32, 8), blk, 0, stream>>>(qbuf, Wkc, qk16,
      64, 512, 512, 4096, 64, 32768, 512, 0, 0, 1.f, 0.f, 1);
  // fused attention (node streamed once; bf16 cache written for logit pass)
  attn_fused<<<dim3(2048), blk, 0, stream>>>(node, qk16, nb16, ctxb);
  // preo[b, head h] = ctx[b,h,:] @ Wvc[head h rows]^T
  gemm_mfma<<<dim3(1, 32, 8), blk, 0, stream>>>(ctxb, Wvc, preo,
      512, 4096, 512, 512, 512, 32768, 64, 0, 1, 1.f, 0.f, 0);
  // qk2 = bf16( SD * preo @ M1 )
  gemm_mfma<<<dim3(8, 32, 1), blk, 0, stream>>>(preo, M1, qk216,
      512, 512, 512, 512, 0, 0, 0, 0, 0, SD, 0.f, 1);
  // fused logit pass
  logits_kernel<<<dim3(2048), dim3(512), 0, stream>>>(nb16, qk216, mask, out);

  (void)in_sizes; (void)n_in; (void)out_size; (void)ws_size;
}

// Round 8
// 294.989 us; speedup vs baseline: 1.7207x; 1.7207x over previous
//
#include <hip/hip_runtime.h>

#define DD 512
#define NNODE 100
#define NH 8

typedef __attribute__((ext_vector_type(4))) float f32x4;
typedef __attribute__((ext_vector_type(8))) short s16x8;

__device__ __forceinline__ unsigned short f2bf(float x) {
  union { float f; unsigned int u; } v; v.f = x;
  unsigned int r = v.u + 0x7fffu + ((v.u >> 16) & 1u);
  return (unsigned short)(r >> 16);
}
__device__ __forceinline__ float bf2f(unsigned short u) {
  union { unsigned int u; float f; } v; v.u = ((unsigned int)u) << 16;
  return v.f;
}

// ---- shared GEMM core: 64x64 tile, 4 waves, bf16 MFMA, 2-phase pipelined ----
struct StageRegs { float4 a4[2]; float as[8]; float4 b4[2]; float bs[8]; };

__device__ __forceinline__ void stage_issue(
    StageRegs& r, const float* __restrict__ A, const float* __restrict__ B,
    const int* __restrict__ gidx, int gmul, int k0, int lda, int ldb,
    int transA, int transB, int m0, int n0)
{
  const int t = threadIdx.x;
  const int tr = t >> 3, kq = t & 7;
  const int bn = t & 63, bk = t >> 6;
  if (!transA) {
#pragma unroll
    for (int rp = 0; rp < 2; ++rp) {
      const int gi = m0 + tr + rp * 32;
      long ab = (long)gi * lda;
      if (gidx) ab += (long)gidx[gi] * gmul;
      r.a4[rp] = *(const float4*)(A + ab + k0 + kq * 4);
    }
  } else {
#pragma unroll
    for (int pp = 0; pp < 8; ++pp)
      r.as[pp] = A[(long)(k0 + bk + pp * 4) * lda + m0 + bn];
  }
  if (transB) {
#pragma unroll
    for (int rp = 0; rp < 2; ++rp)
      r.b4[rp] = *(const float4*)(B + (long)(n0 + tr + rp * 32) * ldb + k0 + kq * 4);
  } else {
#pragma unroll
    for (int pp = 0; pp < 8; ++pp)
      r.bs[pp] = B[(long)(k0 + bk + pp * 4) * ldb + n0 + bn];
  }
}

__device__ __forceinline__ void stage_commit(
    const StageRegs& r, int transA, int transB,
    unsigned short (*As)[40], unsigned short (*Bs)[40])
{
  const int t = threadIdx.x;
  const int tr = t >> 3, kq = t & 7;
  const int bn = t & 63, bk = t >> 6;
  if (!transA) {
#pragma unroll
    for (int rp = 0; rp < 2; ++rp) {
      const float4 av = r.a4[rp];
      unsigned int p0 = (unsigned)f2bf(av.x) | ((unsigned)f2bf(av.y) << 16);
      unsigned int p1 = (unsigned)f2bf(av.z) | ((unsigned)f2bf(av.w) << 16);
      *(uint2*)(&As[tr + rp * 32][kq * 4]) = make_uint2(p0, p1);
    }
  } else {
#pragma unroll
    for (int pp = 0; pp < 8; ++pp) As[bn][bk + pp * 4] = f2bf(r.as[pp]);
  }
  if (transB) {
#pragma unroll
    for (int rp = 0; rp < 2; ++rp) {
      const float4 bv = r.b4[rp];
      unsigned int p0 = (unsigned)f2bf(bv.x) | ((unsigned)f2bf(bv.y) << 16);
      unsigned int p1 = (unsigned)f2bf(bv.z) | ((unsigned)f2bf(bv.w) << 16);
      *(uint2*)(&Bs[tr + rp * 32][kq * 4]) = make_uint2(p0, p1);
    }
  } else {
#pragma unroll
    for (int pp = 0; pp < 8; ++pp) Bs[bn][bk + pp * 4] = f2bf(r.bs[pp]);
  }
}

__device__ __forceinline__ void gemm_core(
    f32x4 acc[2][2], const float* __restrict__ A, const float* __restrict__ B,
    const int* __restrict__ gidx, int gmul, int K, int lda, int ldb,
    int transA, int transB, int m0, int n0,
    unsigned short (*As)[40], unsigned short (*Bs)[40])
{
  const int t = threadIdx.x;
  const int wid = t >> 6, lane = t & 63;
  const int wr = wid >> 1, wc = wid & 1;
  const int r16 = lane & 15, kg = (lane >> 4) * 8;
  StageRegs r;
  stage_issue(r, A, B, gidx, gmul, 0, lda, ldb, transA, transB, m0, n0);
  for (int k0 = 0; k0 < K; k0 += 32) {
    __syncthreads();                       // LDS free (prev tile consumed)
    stage_commit(r, transA, transB, As, Bs);
    __syncthreads();                       // LDS ready
    if (k0 + 32 < K)                       // issue AFTER barrier: stays in flight
      stage_issue(r, A, B, gidx, gmul, k0 + 32, lda, ldb, transA, transB, m0, n0);
    s16x8 a0 = *(const s16x8*)(&As[wr * 32 + r16][kg]);
    s16x8 a1 = *(const s16x8*)(&As[wr * 32 + 16 + r16][kg]);
    s16x8 b0 = *(const s16x8*)(&Bs[wc * 32 + r16][kg]);
    s16x8 b1 = *(const s16x8*)(&Bs[wc * 32 + 16 + r16][kg]);
    acc[0][0] = __builtin_amdgcn_mfma_f32_16x16x32_bf16(a0, b0, acc[0][0], 0, 0, 0);
    acc[0][1] = __builtin_amdgcn_mfma_f32_16x16x32_bf16(a0, b1, acc[0][1], 0, 0, 0);
    acc[1][0] = __builtin_amdgcn_mfma_f32_16x16x32_bf16(a1, b0, acc[1][0], 0, 0, 0);
    acc[1][1] = __builtin_amdgcn_mfma_f32_16x16x32_bf16(a1, b1, acc[1][1], 0, 0, 0);
  }
}

__device__ __forceinline__ void gemm_epilogue(
    f32x4 acc[2][2], void* Cv, int ldc, float alpha, float beta, int obf16,
    int m0, int n0)
{
  const int t = threadIdx.x;
  const int wid = t >> 6, lane = t & 63;
  const int wr = wid >> 1, wc = wid & 1;
  const int r16 = lane & 15;
#pragma unroll
  for (int si = 0; si < 2; ++si)
#pragma unroll
    for (int sj = 0; sj < 2; ++sj)
#pragma unroll
      for (int r = 0; r < 4; ++r) {
        const int row = m0 + wr * 32 + si * 16 + (lane >> 4) * 4 + r;
        const int col = n0 + wc * 32 + sj * 16 + r16;
        const long ci = (long)row * ldc + col;
        float v = alpha * acc[si][sj][r];
        if (obf16) {
          ((unsigned short*)Cv)[ci] = f2bf(v);
        } else {
          float* C = (float*)Cv;
          if (beta != 0.f) v = fmaf(beta, C[ci], v);
          C[ci] = v;
        }
      }
}

__global__ __launch_bounds__(256) void gemm_mfma(
    const float* __restrict__ A, const float* __restrict__ B, void* Cv,
    int K, int lda, int ldb, int ldc,
    long aoffz, long boffz, long coffz,
    int transA, int transB, float alpha, float beta, int obf16)
{
  __shared__ unsigned short As[64][40];
  __shared__ unsigned short Bs[64][40];
  A += (long)blockIdx.z * aoffz;
  B += (long)blockIdx.z * boffz;
  f32x4 acc[2][2] = {};
  gemm_core(acc, A, B, nullptr, 0, K, lda, ldb, transA, transB,
            blockIdx.y * 64, blockIdx.x * 64, As, Bs);
  void* Cz = obf16 ? (void*)((unsigned short*)Cv + (long)blockIdx.z * coffz)
                   : (void*)((float*)Cv + (long)blockIdx.z * coffz);
  gemm_epilogue(acc, Cz, ldc, alpha, beta, obf16, blockIdx.y * 64, blockIdx.x * 64);
}

struct Fold5Args {
  const float* A[5]; const float* B[5]; float* C[5]; float al[5]; int ta[5];
};

// 5 independent 512^3 weight folds (z selects); z may use transA
__global__ __launch_bounds__(256) void fold5_kernel(Fold5Args fa) {
  __shared__ unsigned short As[64][40];
  __shared__ unsigned short Bs[64][40];
  const int z = blockIdx.z;
  f32x4 acc[2][2] = {};
  gemm_core(acc, fa.A[z], fa.B[z], nullptr, 0, 512, 512, 512, fa.ta[z], 0,
            blockIdx.y * 64, blockIdx.x * 64, As, Bs);
  gemm_epilogue(acc, fa.C[z], 512, fa.al[z], 0.f, 0, blockIdx.y * 64, blockIdx.x * 64);
}

// by<32: qbuf = tgt@A1^T + graph@A2^T.  by>=32: M1 = Wo_mha^T @ T1.
__global__ __launch_bounds__(256) void qbufM1_kernel(
    const float* __restrict__ node, const float* __restrict__ graph,
    const int* __restrict__ tidx, const float* __restrict__ A1,
    const float* __restrict__ A2, float* __restrict__ qbuf,
    const float* __restrict__ Wo, const float* __restrict__ T1,
    float* __restrict__ M1)
{
  __shared__ unsigned short As[64][40];
  __shared__ unsigned short Bs[64][40];
  f32x4 acc[2][2] = {};
  const int n0 = blockIdx.x * 64;
  if (blockIdx.y < 32) {
    const int m0 = blockIdx.y * 64;
    gemm_core(acc, node, A1, tidx, DD, DD, NNODE * DD, DD, 0, 1, m0, n0, As, Bs);
    gemm_core(acc, graph, A2, nullptr, 0, DD, DD, DD, 0, 1, m0, n0, As, Bs);
    gemm_epilogue(acc, qbuf, DD, 1.f, 0.f, 0, m0, n0);
  } else {
    const int m0 = (blockIdx.y - 32) * 64;
    gemm_core(acc, Wo, T1, nullptr, 0, 512, 512, 512, 1, 0, m0, n0, As, Bs);
    gemm_epilogue(acc, M1, 512, 1.f, 0.f, 0, m0, n0);
  }
}

// ---- fused attention: single 16KB nf buffer + live prefetch + swizzle.
// One block per batch, 256 thr = 4 waves. NO occupancy cap (R7's
// launch_bounds(256,4) forced 64 VGPRs -> catastrophic spill).
// defer-max rescale (T13, THR=8); no mid-chunk waitcnt drains.
__global__ __launch_bounds__(256) void attn_fused(
    const float* __restrict__ node, const unsigned short* __restrict__ qk16,
    unsigned short* __restrict__ nb16, float* __restrict__ ctx)
{
  const int b = blockIdx.x;
  const int t = threadIdx.x;
  const int lane = t & 63;
  const int wid = t >> 6;
  const int r16 = lane & 15;
  const int rg = lane >> 4;

  __shared__ unsigned short nf[16 * 512];   // 16 KB, slot-swizzled
  __shared__ unsigned short qf[16 * 288];   // 9 KB
  __shared__ float Pl[4][16][8];
  __shared__ float rfl[4][8];

  {
    const unsigned short* qb = qk16 + (long)b * (NH * DD);
    for (int slot = t; slot < 512; slot += 256) {
      const int s = slot >> 5;
      const int idx = slot & 31;           // h*4+g
      const int h = idx >> 2, g = idx & 3;
      *(s16x8*)(&qf[s * 288 + idx * 8 + (idx >> 3) * 8]) =
          *(const s16x8*)(qb + h * DD + s * 32 + g * 8);
    }
  }

  const int r0 = t >> 7;
  const int c4 = (t * 4) & 511;
  const int slotbase = ((c4 >> 3) * 16) + r0;
  const int j_c = c4 & 7;
  const int d0 = t * 2;
  const int cslot0 = (d0 >> 3) * 16;
  const int cxor = (d0 >> 3) & 7;
  const int cj = d0 & 7;
  const int qidx = (r16 & 7) * 4 + rg;
  const int qfb = qidx * 8 + (qidx >> 3) * 8;

  const float* nbase = node + (long)b * (NNODE * DD);
  float4 rs[8];
  {
    const int lim = NNODE * DD;
#pragma unroll
    for (int i = 0; i < 8; ++i) {
      const int e = 4 * t + 1024 * i;
      rs[i] = (e < lim) ? *(const float4*)(nbase + e) : make_float4(0.f, 0.f, 0.f, 0.f);
    }
  }

  float m = -3.0e38f, l = 0.f;
  float2 c2[NH];
#pragma unroll
  for (int h = 0; h < NH; ++h) { c2[h].x = 0.f; c2[h].y = 0.f; }

  for (int c = 0; c < 7; ++c) {
    const int c0 = c * 16;
    // cvt staged regs -> LDS (swizzled) + nb16 global store (issued here so
    // no bf16 state stays live across the barrier; stores drain at barrier)
#pragma unroll
    for (int i = 0; i < 8; ++i) {
      ushort4 h4;
      h4.x = f2bf(rs[i].x); h4.y = f2bf(rs[i].y);
      h4.z = f2bf(rs[i].z); h4.w = f2bf(rs[i].w);
      const int slot = slotbase + 2 * i;
      const int phys = slot ^ ((slot >> 4) & 7);
      *(ushort4*)(&nf[phys * 8 + j_c]) = h4;
      const int row = r0 + 2 * i;
      if (c0 + row < NNODE)
        *(ushort4*)(nb16 + ((long)b * NNODE + c0 + row) * DD + c4) = h4;
    }
    __syncthreads();                        // nf ready (qf too on c==0)
    // issue next-chunk loads AFTER the barrier: stay in flight across compute
    if (c < 6) {
      const int nc0 = c0 + 16;
      const int lim = (NNODE - nc0) * DD;
#pragma unroll
      for (int i = 0; i < 8; ++i) {
        const int e = 4 * t + 1024 * i;
        rs[i] = (e < lim) ? *(const float4*)(nbase + (long)nc0 * DD + e)
                          : make_float4(0.f, 0.f, 0.f, 0.f);
      }
    }

    // scores via MFMA (per-wave redundant; lanes r16>=8 compute dup heads,
    // masked at Pl write)
    f32x4 acc = {0.f, 0.f, 0.f, 0.f};
#pragma unroll
    for (int s = 0; s < 16; ++s) {
      const int slr = (s * 4 + rg) * 16 + r16;
      const s16x8 av = *(const s16x8*)(&nf[(slr ^ ((s * 4 + rg) & 7)) * 8]);
      const s16x8 bv = *(const s16x8*)(&qf[s * 288 + qfb]);
      acc = __builtin_amdgcn_mfma_f32_16x16x32_bf16(av, bv, acc, 0, 0, 0);
    }
#pragma unroll
    for (int r = 0; r < 4; ++r)
      if (c0 + rg * 4 + r >= NNODE) acc[r] = -3.0e38f;

    // online softmax per head col r16; defer-max (THR=8, wave-uniform)
    float cm = fmaxf(fmaxf(acc[0], acc[1]), fmaxf(acc[2], acc[3]));
    cm = fmaxf(cm, __shfl_xor(cm, 16));
    cm = fmaxf(cm, __shfl_xor(cm, 32));
    const bool noresc = (__all(cm <= m + 8.f) != 0);
    if (!noresc) {
      const float mn = fmaxf(m, cm);
      const float rf = __expf(m - mn);
      l *= rf;
      m = mn;
      if (r16 < NH && rg == 0) rfl[wid][r16] = rf;
    }
    float p[4], ps = 0.f;
#pragma unroll
    for (int r = 0; r < 4; ++r) { p[r] = __expf(acc[r] - m); ps += p[r]; }
    ps += __shfl_xor(ps, 16);
    ps += __shfl_xor(ps, 32);
    l += ps;
    if (r16 < NH) {
#pragma unroll
      for (int r = 0; r < 4; ++r) Pl[wid][rg * 4 + r][r16] = p[r];
    }

    // ctx update (swizzled nv reads; Pl reads broadcast — conflict-free)
    if (!noresc) {
      const f32x4 rf0 = *(const f32x4*)(&rfl[wid][0]);
      const f32x4 rf1 = *(const f32x4*)(&rfl[wid][4]);
#pragma unroll
      for (int h = 0; h < 4; ++h) { c2[h].x *= rf0[h]; c2[h].y *= rf0[h]; }
#pragma unroll
      for (int h = 0; h < 4; ++h) { c2[4 + h].x *= rf1[h]; c2[4 + h].y *= rf1[h]; }
    }
#pragma unroll
    for (int n = 0; n < 16; ++n) {
      const int cphys = (cslot0 + n) ^ cxor;
      const unsigned int nv = *(const unsigned int*)(&nf[cphys * 8 + cj]);
      const float x0 = bf2f((unsigned short)(nv & 0xffffu));
      const float x1 = bf2f((unsigned short)(nv >> 16));
      const f32x4 p0 = *(const f32x4*)(&Pl[wid][n][0]);
      const f32x4 p1 = *(const f32x4*)(&Pl[wid][n][4]);
#pragma unroll
      for (int h = 0; h < 4; ++h) {
        c2[h].x = fmaf(p0[h], x0, c2[h].x);
        c2[h].y = fmaf(p0[h], x1, c2[h].y);
        c2[4 + h].x = fmaf(p1[h], x0, c2[4 + h].x);
        c2[4 + h].y = fmaf(p1[h], x1, c2[4 + h].y);
      }
    }
    __syncthreads();                        // nf consumed -> next cvt may write
  }

  if (r16 < NH && rg == 0) rfl[wid][r16] = 1.f / l;
  __builtin_amdgcn_wave_barrier();
  {
    const f32x4 i0 = *(const f32x4*)(&rfl[wid][0]);
    const f32x4 i1 = *(const f32x4*)(&rfl[wid][4]);
    float* cb = ctx + (long)b * (NH * DD) + d0;
#pragma unroll
    for (int h = 0; h < 4; ++h) {
      cb[h * DD] = c2[h].x * i0[h];
      cb[h * DD + 1] = c2[h].y * i0[h];
      cb[(4 + h) * DD] = c2[4 + h].x * i1[h];
      cb[(4 + h) * DD + 1] = c2[4 + h].y * i1[h];
    }
  }
}

// ---- fused logits: MFMA dots from bf16 node + tanh/mask/log_softmax.
// 512 threads: one n-tile per wave (7 of 8 waves), finalize on wave 0.
__global__ __launch_bounds__(512) void logits_kernel(
    const unsigned short* __restrict__ nb16, const unsigned short* __restrict__ qk216,
    const int* __restrict__ mask, float* __restrict__ out)
{
  const int b = blockIdx.x;
  const int t = threadIdx.x;
  const int wid = t >> 6, lane = t & 63;
  const int r16 = lane & 15, rg = lane >> 4;
  __shared__ float sl[112];
  const unsigned short* qb = qk216 + (long)b * DD + rg * 8;

  if (wid < 7) {
    const int ti = wid;
    const int arow = min(ti * 16 + r16, NNODE - 1);
    const unsigned short* ap = nb16 + ((long)b * NNODE + arow) * DD + rg * 8;
    f32x4 acc = {0.f, 0.f, 0.f, 0.f};
#pragma unroll
    for (int s = 0; s < 16; ++s) {
      const s16x8 av = *(const s16x8*)(ap + s * 32);
      const s16x8 bv = *(const s16x8*)(qb + s * 32);
      acc = __builtin_amdgcn_mfma_f32_16x16x32_bf16(av, bv, acc, 0, 0, 0);
    }
    if (r16 == 0) {
#pragma unroll
      for (int r = 0; r < 4; ++r) {
        const int n = ti * 16 + rg * 4 + r;
        if (n < 112) sl[n] = acc[r];
      }
    }
  }
  __syncthreads();
  if (t < 64) {
    float v0 = -3.0e38f, v1 = -3.0e38f;
    if (lane < NNODE)
      v0 = 10.f * tanhf(sl[lane]) - (float)mask[b * NNODE + lane] * 1e9f;
    if (lane + 64 < NNODE)
      v1 = 10.f * tanhf(sl[lane + 64]) - (float)mask[b * NNODE + lane + 64] * 1e9f;
    float mx = fmaxf(v0, v1);
#pragma unroll
    for (int off = 1; off < 64; off <<= 1) mx = fmaxf(mx, __shfl_xor(mx, off));
    float e = 0.f;
    if (lane < NNODE) e += __expf(v0 - mx);
    if (lane + 64 < NNODE) e += __expf(v1 - mx);
#pragma unroll
    for (int off = 1; off < 64; off <<= 1) e += __shfl_xor(e, off);
    const float lse = mx + __logf(e);
    float* ob = out + (long)b * NNODE;
    if (lane < NNODE) ob[lane] = v0 - lse;
    if (lane + 64 < NNODE) ob[lane + 64] = v1 - lse;
  }
}

extern "C" void kernel_launch(void* const* d_in, const int* in_sizes, int n_in,
                              void* d_out, int out_size, void* d_ws, size_t ws_size,
                              hipStream_t stream) {
  const float* node     = (const float*)d_in[0];
  const float* graph    = (const float*)d_in[1];
  const int*   tidx     = (const int*)d_in[2];
  const int*   mask     = (const int*)d_in[3];
  const float* W_target = (const float*)d_in[4];
  const float* W_global = (const float*)d_in[5];
  const float* W_K1     = (const float*)d_in[6];
  const float* W_K2     = (const float*)d_in[7];
  const float* W_Q      = (const float*)d_in[8];
  const float* W_V      = (const float*)d_in[9];
  const float* Wq_mha   = (const float*)d_in[10];
  const float* Wk_mha   = (const float*)d_in[11];
  const float* Wv_mha   = (const float*)d_in[12];
  const float* Wo_mha   = (const float*)d_in[13];
  float* out = (float*)d_out;

  float* base = (float*)d_ws;
  unsigned short* nb16 = (unsigned short*)base;          // 2048*100*512 bf16
  long off = 2048L * NNODE * DD / 2;                     // in floats
  float* A1 = base + off;        off += 262144;
  float* A2 = base + off;        off += 262144;
  float* Wkc = base + off;       off += 262144;
  float* Wvc = base + off;       off += 262144;
  float* T1 = base + off;        off += 262144;
  float* M1 = base + off;        off += 262144;
  float* qbuf = base + off;      off += 2048L * 512;
  unsigned short* qk16 = (unsigned short*)(base + off);  off += 2048L * 4096 / 2;
  float* ctxb = base + off;      off += 2048L * 4096;
  float* preo = base + off;      off += 2048L * 512;
  unsigned short* qk216 = (unsigned short*)(base + off); off += 2048L * 512 / 2;

  dim3 blk(256);
  const float SH = 0.125f;               // 1/sqrt(64)
  const float SD = 0.044194173824f;      // 1/sqrt(512)

  // level-0 folds: A1=Wq@Wt, A2=Wq@Wg, Wkc=SH*(Wk@WK1), Wvc=Wv@WV, T1=W_Q^T@W_K2
  Fold5Args fa;
  fa.A[0] = Wq_mha;  fa.B[0] = W_target; fa.C[0] = A1;  fa.al[0] = 1.f; fa.ta[0] = 0;
  fa.A[1] = Wq_mha;  fa.B[1] = W_global; fa.C[1] = A2;  fa.al[1] = 1.f; fa.ta[1] = 0;
  fa.A[2] = Wk_mha;  fa.B[2] = W_K1;     fa.C[2] = Wkc; fa.al[2] = SH;  fa.ta[2] = 0;
  fa.A[3] = Wv_mha;  fa.B[3] = W_V;      fa.C[3] = Wvc; fa.al[3] = 1.f; fa.ta[3] = 0;
  fa.A[4] = W_Q;     fa.B[4] = W_K2;     fa.C[4] = T1;  fa.al[4] = 1.f; fa.ta[4] = 1;
  fold5_kernel<<<dim3(8, 8, 5), blk, 0, stream>>>(fa);
  // level-1: qbuf (by<32) and M1 = Wo_mha^T @ T1 (by>=32) in one launch
  qbufM1_kernel<<<dim3(8, 40), blk, 0, stream>>>(node, graph, tidx, A1, A2, qbuf,
                                                 Wo_mha, T1, M1);
  // qk16[b,h,:] = bf16( q[b, head h] @ Wkc[head h rows] )
  gemm_mfma<<<dim3(8, 32, 8), blk, 0, stream>>>(qbuf, Wkc, qk16,
      64, 512, 512, 4096, 64, 32768, 512, 0, 0, 1.f, 0.f, 1);
  // fused attention (node streamed once; bf16 cache written for logit pass)
  attn_fused<<<dim3(2048), blk, 0, stream>>>(node, qk16, nb16, ctxb);
  // preo[b, head h] = ctx[b,h,:] @ Wvc[head h rows]^T
  gemm_mfma<<<dim3(1, 32, 8), blk, 0, stream>>>(ctxb, Wvc, preo,
      512, 4096, 512, 512, 512, 32768, 64, 0, 1, 1.f, 0.f, 0);
  // qk2 = bf16( SD * preo @ M1 )
  gemm_mfma<<<dim3(8, 32, 1), blk, 0, stream>>>(preo, M1, qk216,
      512, 512, 512, 512, 0, 0, 0, 0, 0, SD, 0.f, 1);
  // fused logit pass
  logits_kernel<<<dim3(2048), dim3(512), 0, stream>>>(nb16, qk216, mask, out);

  (void)in_sizes; (void)n_in; (void)out_size; (void)ws_size;
}